// Round 6
// baseline (810.557 us; speedup 1.0000x reference)
//
#include <hip/hip_runtime.h>
#include <cmath>

// VanillaRNN: B=256, T=128, D=1, H=2048, C=10
// R17: barrier-minimal epilogue. R14/R16 geometry+protocol (8 groups x 32
// blocks, W fp16 in 128 VGPRs, atomic-exchange publishes committed at MALL,
// relaxed flag RMW after drain, relaxed atomic frag loads), restructured so
// each wave owns its 16x16 output tile END-TO-END:
//   - per-wave transpose through wave-private LDS scratch (DS pipe is
//     in-order within a wave -> no block barrier),
//   - per-wave direct publish of its 64 u64 slots (slot index sigma inverts
//     the validated slab layout),
//   - per-wave explicit s_waitcnt(0) drain (sched_barrier-guarded) then
//     per-(block,wave) MONOTONIC epoch counter signal; consumers poll
//     v >= t on 32 wave-flags (one per lane).
// Block barriers per step: 3 -> 1 (only the k-split reduction barrier).
// red[] is DOUBLE-BUFFERED (red[t&1]): without barriers 2/3 the write of
// iter t+2 races iter t's epilogue reads; the 2-hop flag chain (poll(t+2)
// => producers completed t+1 => they polled ALL group wave-flags >= t+1 =>
// our wave signaled iter t AFTER its red reads) closes it at depth 2.
// hP overwrite safety is 1-hop: flag(Y,*) >= t => Y passed barrier1(t-1)
// => all Y waves' h_{t-2} frag loads returned. LDS: 128K red + 10K Tr +
// 16K xs = 154 KB (1 block/CU, unchanged). Fused projection kept (from Tr).

#define B_ 256
#define T_ 128
#define H_ 2048
#define C_ 10

typedef _Float16 half_t;
typedef _Float16 half8 __attribute__((ext_vector_type(8)));
typedef _Float16 half4v __attribute__((ext_vector_type(4)));
typedef float floatx4 __attribute__((ext_vector_type(4)));
typedef unsigned long long u64;
typedef unsigned long long u64x2 __attribute__((ext_vector_type(2)));

// per-(block,wave) monotonic epoch counter, one 128B line each:
// dword idx = ((g*32 + C)*8 + wave)*32.  256 KB total.
#define FLAG_DWORDS (256 * 8 * 32)

__device__ __forceinline__ float fast_tanh(float v) {
    return 1.0f - 2.0f / (__expf(2.0f * v) + 1.0f);
}

// publish one u64 of packed halfs via RMW (commits+allocates at MALL; the
// returned old value is kept live so the swap cannot be demoted to a
// posted store)
__device__ __forceinline__ void publish_u64(u64* p, u64 v) {
    u64 old = __hip_atomic_exchange(p, v, __ATOMIC_RELAXED,
                                    __HIP_MEMORY_SCOPE_AGENT);
    asm volatile("" :: "v"(old));
}

// wave-level drain: all of this wave's outstanding VMEM (incl. the 64
// lanes' exchange RMWs) committed at the coherence point before anything
// after this line is issued.
__device__ __forceinline__ void wave_drain() {
    __builtin_amdgcn_sched_barrier(0);
    __builtin_amdgcn_s_waitcnt(0);        // vmcnt(0) lgkmcnt(0) expcnt(0)
    __builtin_amdgcn_sched_barrier(0);
}

// ---- persistent RNN kernel: 256 blocks x 512 thr (8 waves, 2/SIMD) ----
__global__ void __launch_bounds__(512, 2) rnn_persist(
    const float* __restrict__ x,   // [B_,T_]
    const float* __restrict__ U,   // [H_]
    const float* __restrict__ W,   // [H_,H_] fp32
    const float* __restrict__ bh,  // [H_]
    const float* __restrict__ V,   // [C_,H_]
    const float* __restrict__ bp,  // [C_]
    half_t* __restrict__ hP0,      // packed state buf 0 (1 MB)
    half_t* __restrict__ hP1,      // packed state buf 1 (1 MB)
    float* __restrict__ hf32,      // d_out h_last region (row-major fp32)
    float* __restrict__ outp,      // d_out projection region [B_,C_] (zeroed)
    unsigned* __restrict__ flags)
{
    const int tid  = threadIdx.x;
    const int wave = tid >> 6, lane = tid & 63;
    const int quad = lane >> 4, lq = lane & 15;
    const int id   = blockIdx.x;
    const int g    = id & 7;                      // group (~XCD under id%8)
    const int C    = id >> 3;                     // block-in-group 0..31
    const int m0   = g * 32;                      // group rows m0..m0+31
    const int n0   = C * 64;                      // block cols n0..n0+63

    // ---- one-time: W frags for this wave's K-range -> regs (fp16) ----
    half8 Bw[8][4];
#pragma unroll
    for (int kk = 0; kk < 8; ++kk) {
#pragma unroll
        for (int nt = 0; nt < 4; ++nt) {
            const int gn = n0 + nt * 16 + lq;
            const int k0 = wave * 256 + kk * 32 + quad * 8;
            const float4 w0 = *(const float4*)&W[(size_t)gn * H_ + k0];
            const float4 w1 = *(const float4*)&W[(size_t)gn * H_ + k0 + 4];
            const float wv[8] = {w0.x, w0.y, w0.z, w0.w, w1.x, w1.y, w1.z, w1.w};
            half8 hw;
#pragma unroll
            for (int j = 0; j < 8; ++j) hw[j] = (half_t)wv[j];
            Bw[kk][nt] = hw;
        }
    }

    // epilogue-owner role: wave w owns output tile (mtO, ntO); 2x4 = 8 tiles
    const int mtO = wave & 1, ntO = wave >> 1;
    const float uvO = U[n0 + ntO * 16 + lq];
    const float bvO = bh[n0 + ntO * 16 + lq];

    __shared__ floatx4 red[2][2][8][4][64];       // DOUBLE-buffered, 128 KB
    __shared__ __align__(16) float Tr[8][16][20]; // per-wave transpose, 10 KB
    __shared__ float xs[T_][32];                  // x slab transposed, 16 KB

    for (int i = tid; i < 32 * T_; i += 512) {    // one-time x staging
        const int r = i & 31, tt = i >> 5;
        xs[tt][r] = x[(size_t)(m0 + r) * T_ + tt];
    }
    __syncthreads();

    // step-0 producer mapping (per-thread, validated): u64 index == tid
    const int prow = (tid >> 8) * 16 + ((tid >> 1) & 15);   // local row 0..31
    const int pcol = ((tid >> 7) & 1) * 32 + ((tid >> 5) & 3) * 8 + (tid & 1) * 4;
    const size_t slab = (size_t)g * 16384;                  // u64 units (128 KB)
    const size_t pdst = slab + (size_t)C * 512 + tid;
    const size_t cbase = slab + (size_t)wave * 2048 + (size_t)lane * 2;

    // owner-publish slot: inverts the slab layout for (row mtO*16+lq,
    // cols ntO*16 + quad*4 .. +3)
    const int sigma = mtO * 256 + (ntO >> 1) * 128
                    + ((ntO & 1) * 2 + (quad >> 1)) * 32 + lq * 2 + (quad & 1);
    const size_t pdst_o = slab + (size_t)C * 512 + sigma;

    // flag addresses (monotonic epoch counters)
    unsigned* myflag = flags + (((size_t)(g * 32 + C)) * 8 + wave) * 32;
    const unsigned* pollp = flags
        + (((size_t)(g * 32 + wave * 4 + ((lane >> 3) & 3))) * 8 + (lane & 7)) * 32;

    // ---- step 0: h1 = tanh(x*U + bh) -> packed hP1, signal epoch 1 ----
    {
        const float xb = xs[0][prow];
        half4v hv;
#pragma unroll
        for (int j = 0; j < 4; ++j) {
            const int n = n0 + pcol + j;
            hv[j] = (half_t)fast_tanh(xb * U[n] + bh[n]);
        }
        publish_u64((u64*)hP1 + pdst, __builtin_bit_cast(u64, hv));
    }
    wave_drain();                 // this wave's 64 publishes committed
    if (lane == 0)
        __hip_atomic_fetch_add(myflag, 1u, __ATOMIC_RELAXED,
                               __HIP_MEMORY_SCOPE_AGENT);

    // ---- steps t = 1..127 ----
    for (int t = 1; t < T_; ++t) {
        const half_t* hin = (t & 1) ? hP1 : hP0;  // h_t (packed)
        half_t* hout      = (t & 1) ? hP0 : hP1;  // h_{t+1} (packed)
        const u64* pw = (const u64*)hin + cbase;

        // poll the 32 wave-flags of my 4 producers: epoch >= t
        {
            while (true) {
                const unsigned v = __hip_atomic_load(pollp, __ATOMIC_RELAXED,
                                                     __HIP_MEMORY_SCOPE_AGENT);
                if (__all(v >= (unsigned)t)) break;
                __builtin_amdgcn_s_sleep(1);
            }
            asm volatile("" ::: "memory");        // no load hoisting above poll
        }

        floatx4 acc[2][4] = {};

        u64 rl[8], rh[8];                         // ring-8 of 16B frags
        auto issue = [&](int f) {
            // f -> (c'=f>>2, mt=(f>>1)&1, kc=f&1)
            const u64* q = pw + (size_t)((f >> 2) * 512 + ((f >> 1) & 1) * 256
                                         + (f & 1) * 128);
            rl[f & 7] = __hip_atomic_load(q, __ATOMIC_RELAXED,
                                          __HIP_MEMORY_SCOPE_AGENT);
            rh[f & 7] = __hip_atomic_load(q + 1, __ATOMIC_RELAXED,
                                          __HIP_MEMORY_SCOPE_AGENT);
        };
#pragma unroll
        for (int f = 0; f < 8; ++f) issue(f);
#pragma unroll
        for (int f = 0; f < 16; ++f) {            // 16 A-frags
            const int cp = f >> 2, mt = (f >> 1) & 1, kc = f & 1;
            const int kk = cp * 2 + kc;
            u64x2 bits; bits.x = rl[f & 7]; bits.y = rh[f & 7];
            const half8 av = __builtin_bit_cast(half8, bits);
            if (f + 8 < 16) issue(f + 8);
            acc[mt][0] = __builtin_amdgcn_mfma_f32_16x16x32_f16(av, Bw[kk][0], acc[mt][0], 0, 0, 0);
            acc[mt][1] = __builtin_amdgcn_mfma_f32_16x16x32_f16(av, Bw[kk][1], acc[mt][1], 0, 0, 0);
            acc[mt][2] = __builtin_amdgcn_mfma_f32_16x16x32_f16(av, Bw[kk][2], acc[mt][2], 0, 0, 0);
            acc[mt][3] = __builtin_amdgcn_mfma_f32_16x16x32_f16(av, Bw[kk][3], acc[mt][3], 0, 0, 0);
        }

        // ---- 8-way K-split reduction (double-buffered) ----
#pragma unroll
        for (int mt = 0; mt < 2; ++mt)
#pragma unroll
            for (int nt = 0; nt < 4; ++nt)
                red[t & 1][mt][wave][nt][lane] = acc[mt][nt];
        __syncthreads();                          // ONLY block barrier per step

        // ---- per-wave owner epilogue: sum, tanh, transpose, publish ----
        {
            float xr[4];
#pragma unroll
            for (int r = 0; r < 4; ++r) xr[r] = xs[t][mtO * 16 + quad * 4 + r];
            floatx4 s = red[t & 1][mtO][0][ntO][lane];
#pragma unroll
            for (int ww = 1; ww < 8; ++ww) s += red[t & 1][mtO][ww][ntO][lane];
#pragma unroll
            for (int r = 0; r < 4; ++r) {
                const float pre = s[r] + xr[r] * uvO + bvO;
                Tr[wave][quad * 4 + r][lq] = fast_tanh(pre);   // wave-private
            }
            // DS pipe is in-order within a wave: read back transposed
            const float4 fr = *(const float4*)&Tr[wave][lq][quad * 4];

            if (t < T_ - 1) {
                half4v hv;
                hv[0] = (half_t)fr.x; hv[1] = (half_t)fr.y;
                hv[2] = (half_t)fr.z; hv[3] = (half_t)fr.w;
                publish_u64((u64*)hout + pdst_o, __builtin_bit_cast(u64, hv));
                wave_drain();         // this wave's publishes committed
                if (lane == 0)
                    __hip_atomic_fetch_add(myflag, 1u, __ATOMIC_RELAXED,
                                           __HIP_MEMORY_SCOPE_AGENT);
            } else {
                // final h_128 -> d_out fp32 (row m0+mtO*16+lq, col n0+ntO*16+quad*4)
                float* fd = hf32 + (size_t)(m0 + mtO * 16 + lq) * H_
                          + n0 + ntO * 16 + quad * 4;
                *(float4*)fd = make_float4(fr.x, fr.y, fr.z, fr.w);
                __syncthreads();      // all waves' Tr tiles complete
                // fused projection: partial out[32,10] = Tr-tiles @ V^T
                if (tid < 32 * C_) {
                    const int r = tid & 31, c = tid >> 5;    // c in [0,10)
                    float sacc = (C == 0) ? bp[c] : 0.0f;
                    const float* vr = V + (size_t)c * H_ + n0;
#pragma unroll 8
                    for (int n = 0; n < 64; ++n)
                        sacc += Tr[(n >> 4) * 2 + (r >> 4)][r & 15][n & 15] * vr[n];
                    atomicAdd(&outp[(size_t)(m0 + r) * C_ + c], sacc);
                }
            }
        }
    }
}

extern "C" void kernel_launch(void* const* d_in, const int* in_sizes, int n_in,
                              void* d_out, int out_size, void* d_ws, size_t ws_size,
                              hipStream_t stream) {
    const float* x  = (const float*)d_in[0];
    const float* U  = (const float*)d_in[1];
    const float* W  = (const float*)d_in[2];
    const float* V  = (const float*)d_in[3];
    const float* bh = (const float*)d_in[4];
    const float* bp = (const float*)d_in[5];

    float* out_h = (float*)d_out;                 // [B_*H_] fp32 h_last
    float* outp  = out_h + (size_t)B_ * H_;       // [B_*C_]

    half_t* hP0 = (half_t*)d_ws;                                   // 1 MB packed
    half_t* hP1 = hP0 + (size_t)B_ * H_;                           // 1 MB packed
    unsigned* flags = (unsigned*)((char*)d_ws + 2u * 1024 * 1024); // 256 KB

    hipMemsetAsync(flags, 0, FLAG_DWORDS * sizeof(unsigned), stream);
    hipMemsetAsync(outp, 0, (size_t)B_ * C_ * sizeof(float), stream);

    rnn_persist<<<dim3(256), dim3(512), 0, stream>>>(
        x, U, W, bh, V, bp, hP0, hP1, out_h, outp, flags);
}

// Round 7
// 649.961 us; speedup vs baseline: 1.2471x; 1.2471x over previous
//
#include <hip/hip_runtime.h>
#include <cmath>

// VanillaRNN: B=256, T=128, D=1, H=2048, C=10
// R18: recombination of validated winners only.
//  - R16 protocol (622-us-class): per-t flag lines, single tid0 flag RMW
//    after a draining __syncthreads, consumers poll 4 lines/wave v>=1 with
//    relaxed agent atomics, ring-8 atomic frag loads, atomic-exchange
//    publishes (commit at MALL, returned value kept live).
//  - R17's owner-direct epilogue (correctness-validated there): each wave
//    owns its 16x16 tile end-to-end — sums the 8-way K-split from red,
//    tanh, transposes through WAVE-PRIVATE Tr (no block barrier; DS
//    in-order within wave), publishes its own 64 u64s at the sigma slot
//    (inverse of the consumer slab layout).
//  - R17's distributed per-wave flags are REVERTED (they 8x'd flag RMWs
//    and poll line-touches at the MALL -> 630->789 regression).
// Barriers/step: 2 (red-ready A; drain-before-flag B). Overwrite safety:
// publishes occur after barrier A, which follows the collective
// observation of all 32 group flags(t-1) (8 waves x 4 each) => every
// group block finished its h_{t-1} reads (their loads completed before
// their own barrier A(t-1), flag(t-1) after their barrier B(t-1)).
// red[] single-buffered: next iter's red writes happen only after ALL
// waves passed barrier B (flag step), which is after owner red reads.
// Fused projection + h_last store from Tr at t=127 (R17-validated).

#define B_ 256
#define T_ 128
#define H_ 2048
#define C_ 10

typedef _Float16 half_t;
typedef _Float16 half8 __attribute__((ext_vector_type(8)));
typedef _Float16 half4v __attribute__((ext_vector_type(4)));
typedef float floatx4 __attribute__((ext_vector_type(4)));
typedef unsigned long long u64;
typedef unsigned long long u64x2 __attribute__((ext_vector_type(2)));

// flag array: dword index  t*(8*32*32) + (g*32 + C)*32  (one 128B line per
// flag). t in [0,127), g in [0,8), C = producer block-in-group [0,32).
#define FLAG_DWORDS (128 * 8 * 32 * 32)   // 4 MB

__device__ __forceinline__ float fast_tanh(float v) {
    return 1.0f - 2.0f / (__expf(2.0f * v) + 1.0f);
}

// publish one u64 of packed halfs via RMW (commits+allocates at MALL; the
// returned old value is kept live so the swap cannot be demoted to a
// posted store)
__device__ __forceinline__ void publish_u64(u64* p, u64 v) {
    u64 old = __hip_atomic_exchange(p, v, __ATOMIC_RELAXED,
                                    __HIP_MEMORY_SCOPE_AGENT);
    asm volatile("" :: "v"(old));
}

// ---- persistent RNN kernel: 256 blocks x 512 thr (8 waves, 2/SIMD) ----
__global__ void __launch_bounds__(512, 2) rnn_persist(
    const float* __restrict__ x,   // [B_,T_]
    const float* __restrict__ U,   // [H_]
    const float* __restrict__ W,   // [H_,H_] fp32
    const float* __restrict__ bh,  // [H_]
    const float* __restrict__ V,   // [C_,H_]
    const float* __restrict__ bp,  // [C_]
    half_t* __restrict__ hP0,      // packed state buf 0 (1 MB)
    half_t* __restrict__ hP1,      // packed state buf 1 (1 MB)
    float* __restrict__ hf32,      // d_out h_last region (row-major fp32)
    float* __restrict__ outp,      // d_out projection region [B_,C_] (zeroed)
    unsigned* __restrict__ flags)
{
    const int tid  = threadIdx.x;
    const int wave = tid >> 6, lane = tid & 63;
    const int quad = lane >> 4, lq = lane & 15;
    const int id   = blockIdx.x;
    const int g    = id & 7;                      // group (~XCD under id%8)
    const int C    = id >> 3;                     // block-in-group 0..31
    const int m0   = g * 32;                      // group rows m0..m0+31
    const int n0   = C * 64;                      // block cols n0..n0+63

    // ---- one-time: W frags for this wave's K-range -> regs (fp16) ----
    half8 Bw[8][4];
#pragma unroll
    for (int kk = 0; kk < 8; ++kk) {
#pragma unroll
        for (int nt = 0; nt < 4; ++nt) {
            const int gn = n0 + nt * 16 + lq;
            const int k0 = wave * 256 + kk * 32 + quad * 8;
            const float4 w0 = *(const float4*)&W[(size_t)gn * H_ + k0];
            const float4 w1 = *(const float4*)&W[(size_t)gn * H_ + k0 + 4];
            const float wv[8] = {w0.x, w0.y, w0.z, w0.w, w1.x, w1.y, w1.z, w1.w};
            half8 hw;
#pragma unroll
            for (int j = 0; j < 8; ++j) hw[j] = (half_t)wv[j];
            Bw[kk][nt] = hw;
        }
    }

    // epilogue-owner role: wave w owns output tile (mtO, ntO); 2x4 = 8 tiles
    const int mtO = wave & 1, ntO = wave >> 1;
    const float uvO = U[n0 + ntO * 16 + lq];
    const float bvO = bh[n0 + ntO * 16 + lq];

    __shared__ floatx4 red[2][8][4][64];          // 8-way k-split, 64 KB
    __shared__ __align__(16) float Tr[8][16][20]; // per-wave transpose, 10 KB
    __shared__ float xs[T_][32];                  // x slab transposed, 16 KB

    for (int i = tid; i < 32 * T_; i += 512) {    // one-time x staging
        const int r = i & 31, tt = i >> 5;
        xs[tt][r] = x[(size_t)(m0 + r) * T_ + tt];
    }
    __syncthreads();

    // step-0 producer mapping (validated): u64 index == tid
    const int prow = (tid >> 8) * 16 + ((tid >> 1) & 15);   // local row 0..31
    const int pcol = ((tid >> 7) & 1) * 32 + ((tid >> 5) & 3) * 8 + (tid & 1) * 4;
    const size_t slab = (size_t)g * 16384;                  // u64 units (128 KB)
    const size_t pdst = slab + (size_t)C * 512 + tid;
    const size_t cbase = slab + (size_t)wave * 2048 + (size_t)lane * 2;

    // owner-publish slot (R17-validated sigma): row mtO*16+lq,
    // cols ntO*16 + quad*4 .. +3
    const int sigma = mtO * 256 + (ntO >> 1) * 128
                    + ((ntO & 1) * 2 + (quad >> 1)) * 32 + lq * 2 + (quad & 1);
    const size_t pdst_o = slab + (size_t)C * 512 + sigma;

    // flag addresses (R16 layout: one per-t line per block)
    unsigned* myflag_base = flags + ((size_t)g * 32 + C) * 32;   // + t*8192
    const unsigned* pollp = flags + ((size_t)g * 32 + wave * 4 + (lane & 3)) * 32;

    // ---- step 0: h1 = tanh(x*U + bh) -> packed hP1, signal slot 0 ----
    {
        const float xb = xs[0][prow];
        half4v hv;
#pragma unroll
        for (int j = 0; j < 4; ++j) {
            const int n = n0 + pcol + j;
            hv[j] = (half_t)fast_tanh(xb * U[n] + bh[n]);
        }
        publish_u64((u64*)hP1 + pdst, __builtin_bit_cast(u64, hv));
    }
    __syncthreads();          // drains vmcnt: all exchanges committed at MALL
    if (tid == 0)
        __hip_atomic_fetch_add(myflag_base, 1u, __ATOMIC_RELAXED,
                               __HIP_MEMORY_SCOPE_AGENT);

    // ---- steps t = 1..127 ----
    for (int t = 1; t < T_; ++t) {
        const half_t* hin = (t & 1) ? hP1 : hP0;  // h_t (packed)
        half_t* hout      = (t & 1) ? hP0 : hP1;  // h_{t+1} (packed)
        const u64* pw = (const u64*)hin + cbase;

        // wave-level poll: my 4 producers for slot t-1 (v >= 1)
        {
            const unsigned* fp = pollp + (size_t)(t - 1) * (8 * 32 * 32);
            while (true) {
                const unsigned v = __hip_atomic_load(fp, __ATOMIC_RELAXED,
                                                     __HIP_MEMORY_SCOPE_AGENT);
                if (__all(v >= 1u)) break;
                __builtin_amdgcn_s_sleep(1);
            }
            asm volatile("" ::: "memory");        // no load hoisting above poll
        }

        floatx4 acc[2][4] = {};

        u64 rl[8], rh[8];                         // ring-8 of 16B frags
        auto issue = [&](int f) {
            // f -> (c'=f>>2, mt=(f>>1)&1, kc=f&1)
            const u64* q = pw + (size_t)((f >> 2) * 512 + ((f >> 1) & 1) * 256
                                         + (f & 1) * 128);
            rl[f & 7] = __hip_atomic_load(q, __ATOMIC_RELAXED,
                                          __HIP_MEMORY_SCOPE_AGENT);
            rh[f & 7] = __hip_atomic_load(q + 1, __ATOMIC_RELAXED,
                                          __HIP_MEMORY_SCOPE_AGENT);
        };
#pragma unroll
        for (int f = 0; f < 8; ++f) issue(f);
#pragma unroll
        for (int f = 0; f < 16; ++f) {            // 16 A-frags
            const int cp = f >> 2, mt = (f >> 1) & 1, kc = f & 1;
            const int kk = cp * 2 + kc;
            u64x2 bits; bits.x = rl[f & 7]; bits.y = rh[f & 7];
            const half8 av = __builtin_bit_cast(half8, bits);
            if (f + 8 < 16) issue(f + 8);
            acc[mt][0] = __builtin_amdgcn_mfma_f32_16x16x32_f16(av, Bw[kk][0], acc[mt][0], 0, 0, 0);
            acc[mt][1] = __builtin_amdgcn_mfma_f32_16x16x32_f16(av, Bw[kk][1], acc[mt][1], 0, 0, 0);
            acc[mt][2] = __builtin_amdgcn_mfma_f32_16x16x32_f16(av, Bw[kk][2], acc[mt][2], 0, 0, 0);
            acc[mt][3] = __builtin_amdgcn_mfma_f32_16x16x32_f16(av, Bw[kk][3], acc[mt][3], 0, 0, 0);
        }

        // ---- 8-way K-split reduction ----
#pragma unroll
        for (int mt = 0; mt < 2; ++mt)
#pragma unroll
            for (int nt = 0; nt < 4; ++nt)
                red[mt][wave][nt][lane] = acc[mt][nt];
        __syncthreads();                          // barrier A (red ready;
                                                  // also: all 32 flags seen)

        // ---- per-wave owner epilogue: sum, tanh, transpose, publish ----
        {
            float xr[4];
#pragma unroll
            for (int r = 0; r < 4; ++r) xr[r] = xs[t][mtO * 16 + quad * 4 + r];
            floatx4 s = red[mtO][0][ntO][lane];
#pragma unroll
            for (int ww = 1; ww < 8; ++ww) s += red[mtO][ww][ntO][lane];
#pragma unroll
            for (int r = 0; r < 4; ++r) {
                const float pre = s[r] + xr[r] * uvO + bvO;
                Tr[wave][quad * 4 + r][lq] = fast_tanh(pre);   // wave-private
            }
            // DS pipe is in-order within a wave: read back transposed
            const float4 fr = *(const float4*)&Tr[wave][lq][quad * 4];

            if (t < T_ - 1) {
                half4v hv;
                hv[0] = (half_t)fr.x; hv[1] = (half_t)fr.y;
                hv[2] = (half_t)fr.z; hv[3] = (half_t)fr.w;
                publish_u64((u64*)hout + pdst_o, __builtin_bit_cast(u64, hv));
                __syncthreads();      // barrier B: drains ALL waves' vmcnt
                if (tid == 0)         // single aggregated signal
                    __hip_atomic_fetch_add(
                        myflag_base + (size_t)t * (8 * 32 * 32), 1u,
                        __ATOMIC_RELAXED, __HIP_MEMORY_SCOPE_AGENT);
            } else {
                // final h_128 -> d_out fp32
                float* fd = hf32 + (size_t)(m0 + mtO * 16 + lq) * H_
                          + n0 + ntO * 16 + quad * 4;
                *(float4*)fd = make_float4(fr.x, fr.y, fr.z, fr.w);
                __syncthreads();      // all waves' Tr tiles complete
                // fused projection: partial out[32,10] = Tr-tiles @ V^T
                if (tid < 32 * C_) {
                    const int r = tid & 31, c = tid >> 5;    // c in [0,10)
                    float sacc = (C == 0) ? bp[c] : 0.0f;
                    const float* vr = V + (size_t)c * H_ + n0;
#pragma unroll 8
                    for (int n = 0; n < 64; ++n)
                        sacc += Tr[(n >> 4) * 2 + (r >> 4)][r & 15][n & 15] * vr[n];
                    atomicAdd(&outp[(size_t)(m0 + r) * C_ + c], sacc);
                }
            }
        }
    }
}

extern "C" void kernel_launch(void* const* d_in, const int* in_sizes, int n_in,
                              void* d_out, int out_size, void* d_ws, size_t ws_size,
                              hipStream_t stream) {
    const float* x  = (const float*)d_in[0];
    const float* U  = (const float*)d_in[1];
    const float* W  = (const float*)d_in[2];
    const float* V  = (const float*)d_in[3];
    const float* bh = (const float*)d_in[4];
    const float* bp = (const float*)d_in[5];

    float* out_h = (float*)d_out;                 // [B_*H_] fp32 h_last
    float* outp  = out_h + (size_t)B_ * H_;       // [B_*C_]

    half_t* hP0 = (half_t*)d_ws;                                   // 1 MB packed
    half_t* hP1 = hP0 + (size_t)B_ * H_;                           // 1 MB packed
    unsigned* flags = (unsigned*)((char*)d_ws + 2u * 1024 * 1024); // 4 MB

    hipMemsetAsync(flags, 0, FLAG_DWORDS * sizeof(unsigned), stream);
    hipMemsetAsync(outp, 0, (size_t)B_ * C_ * sizeof(float), stream);

    rnn_persist<<<dim3(256), dim3(512), 0, stream>>>(
        x, U, W, bh, V, bp, hP0, hP1, out_h, outp, flags);
}

// Round 8
// 587.094 us; speedup vs baseline: 1.3806x; 1.1071x over previous
//
#include <hip/hip_runtime.h>
#include <cmath>

// VanillaRNN: B=256, T=128, D=1, H=2048, C=10
// R19: ADDRESS-ROTATED h exchange = L2 sharing without fences.
// R18 floor analysis: ~4.8 us/step = bulk 32 MB/step fabric broadcast
// (~3.2 us at ~1 TB/s/XCD ingress) + sync ~1.0 + LDS red ~0.4 + MFMA ~0.3.
// The 32x read redundancy (each slab line read by all 32 group blocks) is
// only un-cacheable because ping-pong buffers REUSE addresses (stale-line
// hazard; R15's fence fix cost 4.6x). Rotation removes reuse: step s
// publishes into its own 1 MB buffer hP[s] (127 slots). A plain cached
// consumer load can then never hit a stale line: every L2 fill of an hP[s]
// line happens after some same-XCD block observed flag(s) (all blocks poll
// before reading) => fill pulls MALL-committed data; later same-XCD reads
// are L2 hits. Fabric traffic: 32 MB/step -> <=8 MB worst-case placement,
// ~1 MB with id%8 grouping.
// Protocol is EXACTLY R18 (unchanged, validated): atomic-exchange
// publishes (commit+allocate at MALL, returned value kept live),
// __syncthreads vmcnt drain, single tid0 relaxed flag RMW per per-t line,
// consumers poll 4 lines/wave v>=1 with relaxed agent atomics. Only the
// consumer DATA loads switch to plain dwordx4 (ROT=1). If ws_size < 131 MB
// the ROT=0 instantiation (2-buffer ping-pong + atomic loads, == R18) runs.
// Epilogue (R17/R18-validated): per-wave owner tile, wave-private Tr
// transpose, sigma-slot publish, fused V-projection + h_last at t=127.

#define B_ 256
#define T_ 128
#define H_ 2048
#define C_ 10

typedef _Float16 half_t;
typedef _Float16 half8 __attribute__((ext_vector_type(8)));
typedef _Float16 half4v __attribute__((ext_vector_type(4)));
typedef float floatx4 __attribute__((ext_vector_type(4)));
typedef unsigned long long u64;
typedef unsigned long long u64x2 __attribute__((ext_vector_type(2)));

#define BUF_U64 131072        // one h buffer: 256*2048 halfs = 1 MB
#define NSLOT 127             // published slots 0..126

// flag array: dword index  t*(8*32*32) + (g*32 + C)*32  (one 128B line per
// flag). t in [0,127), g in [0,8), C = producer block-in-group [0,32).
#define FLAG_DWORDS (128 * 8 * 32 * 32)   // 4 MB

__device__ __forceinline__ float fast_tanh(float v) {
    return 1.0f - 2.0f / (__expf(2.0f * v) + 1.0f);
}

// publish one u64 of packed halfs via RMW (commits+allocates at MALL; the
// returned old value is kept live so the swap cannot be demoted to a
// posted store)
__device__ __forceinline__ void publish_u64(u64* p, u64 v) {
    u64 old = __hip_atomic_exchange(p, v, __ATOMIC_RELAXED,
                                    __HIP_MEMORY_SCOPE_AGENT);
    asm volatile("" :: "v"(old));
}

// slab base (u64 units) of published slot s
template <int ROT>
__device__ __forceinline__ size_t slot_base(int s) {
    return ROT ? (size_t)s * BUF_U64
               : (size_t)((s + 1) & 1) * BUF_U64;   // legacy ping-pong
}

// ---- persistent RNN kernel: 256 blocks x 512 thr (8 waves, 2/SIMD) ----
template <int ROT>
__global__ void __launch_bounds__(512, 2) rnn_persist(
    const float* __restrict__ x,   // [B_,T_]
    const float* __restrict__ U,   // [H_]
    const float* __restrict__ W,   // [H_,H_] fp32
    const float* __restrict__ bh,  // [H_]
    const float* __restrict__ V,   // [C_,H_]
    const float* __restrict__ bp,  // [C_]
    half_t* __restrict__ hbase,    // ROT: 127 x 1 MB slots; else 2 x 1 MB
    float* __restrict__ hf32,      // d_out h_last region (row-major fp32)
    float* __restrict__ outp,      // d_out projection region [B_,C_] (zeroed)
    unsigned* __restrict__ flags)
{
    const int tid  = threadIdx.x;
    const int wave = tid >> 6, lane = tid & 63;
    const int quad = lane >> 4, lq = lane & 15;
    const int id   = blockIdx.x;
    const int g    = id & 7;                      // group (~XCD under id%8)
    const int C    = id >> 3;                     // block-in-group 0..31
    const int m0   = g * 32;                      // group rows m0..m0+31
    const int n0   = C * 64;                      // block cols n0..n0+63

    // ---- one-time: W frags for this wave's K-range -> regs (fp16) ----
    half8 Bw[8][4];
#pragma unroll
    for (int kk = 0; kk < 8; ++kk) {
#pragma unroll
        for (int nt = 0; nt < 4; ++nt) {
            const int gn = n0 + nt * 16 + lq;
            const int k0 = wave * 256 + kk * 32 + quad * 8;
            const float4 w0 = *(const float4*)&W[(size_t)gn * H_ + k0];
            const float4 w1 = *(const float4*)&W[(size_t)gn * H_ + k0 + 4];
            const float wv[8] = {w0.x, w0.y, w0.z, w0.w, w1.x, w1.y, w1.z, w1.w};
            half8 hw;
#pragma unroll
            for (int j = 0; j < 8; ++j) hw[j] = (half_t)wv[j];
            Bw[kk][nt] = hw;
        }
    }

    // epilogue-owner role: wave w owns output tile (mtO, ntO); 2x4 = 8 tiles
    const int mtO = wave & 1, ntO = wave >> 1;
    const float uvO = U[n0 + ntO * 16 + lq];
    const float bvO = bh[n0 + ntO * 16 + lq];

    __shared__ floatx4 red[2][8][4][64];          // 8-way k-split, 64 KB
    __shared__ __align__(16) float Tr[8][16][20]; // per-wave transpose, 10 KB
    __shared__ float xs[T_][32];                  // x slab transposed, 16 KB

    for (int i = tid; i < 32 * T_; i += 512) {    // one-time x staging
        const int r = i & 31, tt = i >> 5;
        xs[tt][r] = x[(size_t)(m0 + r) * T_ + tt];
    }
    __syncthreads();

    // step-0 producer mapping (validated): u64 index == tid
    const int prow = (tid >> 8) * 16 + ((tid >> 1) & 15);   // local row 0..31
    const int pcol = ((tid >> 7) & 1) * 32 + ((tid >> 5) & 3) * 8 + (tid & 1) * 4;
    const size_t slab = (size_t)g * 16384;                  // u64 units (128 KB)
    const size_t pdst = slab + (size_t)C * 512 + tid;       // within-buffer
    const size_t cbase = slab + (size_t)wave * 2048 + (size_t)lane * 2;

    // owner-publish slot (R17-validated sigma): row mtO*16+lq,
    // cols ntO*16 + quad*4 .. +3
    const int sigma = mtO * 256 + (ntO >> 1) * 128
                    + ((ntO & 1) * 2 + (quad >> 1)) * 32 + lq * 2 + (quad & 1);
    const size_t pdst_o = slab + (size_t)C * 512 + sigma;

    // flag addresses (one per-t 128B line per block)
    unsigned* myflag_base = flags + ((size_t)g * 32 + C) * 32;   // + t*8192
    const unsigned* pollp = flags + ((size_t)g * 32 + wave * 4 + (lane & 3)) * 32;

    // ---- step 0: h1 = tanh(x*U + bh) -> slot 0, signal ----
    {
        const float xb = xs[0][prow];
        half4v hv;
#pragma unroll
        for (int j = 0; j < 4; ++j) {
            const int n = n0 + pcol + j;
            hv[j] = (half_t)fast_tanh(xb * U[n] + bh[n]);
        }
        publish_u64((u64*)hbase + slot_base<ROT>(0) + pdst,
                    __builtin_bit_cast(u64, hv));
    }
    __syncthreads();          // drains vmcnt: all exchanges committed at MALL
    if (tid == 0)
        __hip_atomic_fetch_add(myflag_base, 1u, __ATOMIC_RELAXED,
                               __HIP_MEMORY_SCOPE_AGENT);

    // ---- steps t = 1..127 : consume slot t-1, publish slot t ----
    for (int t = 1; t < T_; ++t) {
        const u64* pw = (const u64*)hbase + slot_base<ROT>(t - 1) + cbase;
        u64* pout     = (u64*)hbase + slot_base<ROT>(t);

        // wave-level poll: my 4 producers for slot t-1 (v >= 1)
        {
            const unsigned* fp = pollp + (size_t)(t - 1) * (8 * 32 * 32);
            while (true) {
                const unsigned v = __hip_atomic_load(fp, __ATOMIC_RELAXED,
                                                     __HIP_MEMORY_SCOPE_AGENT);
                if (__all(v >= 1u)) break;
                __builtin_amdgcn_s_sleep(1);
            }
            asm volatile("" ::: "memory");        // no load hoisting above poll
        }

        floatx4 acc[2][4] = {};

        u64 rl[8], rh[8];                         // ring-8 of 16B frags
        auto issue = [&](int f) {
            // f -> (c'=f>>2, mt=(f>>1)&1, kc=f&1)
            const u64* q = pw + (size_t)((f >> 2) * 512 + ((f >> 1) & 1) * 256
                                         + (f & 1) * 128);
            if (ROT) {
                const u64x2 v = *(const u64x2*)q; // plain cached dwordx4
                rl[f & 7] = v.x;
                rh[f & 7] = v.y;
            } else {
                rl[f & 7] = __hip_atomic_load(q, __ATOMIC_RELAXED,
                                              __HIP_MEMORY_SCOPE_AGENT);
                rh[f & 7] = __hip_atomic_load(q + 1, __ATOMIC_RELAXED,
                                              __HIP_MEMORY_SCOPE_AGENT);
            }
        };
#pragma unroll
        for (int f = 0; f < 8; ++f) issue(f);
#pragma unroll
        for (int f = 0; f < 16; ++f) {            // 16 A-frags
            const int cp = f >> 2, mt = (f >> 1) & 1, kc = f & 1;
            const int kk = cp * 2 + kc;
            u64x2 bits; bits.x = rl[f & 7]; bits.y = rh[f & 7];
            const half8 av = __builtin_bit_cast(half8, bits);
            if (f + 8 < 16) issue(f + 8);
            acc[mt][0] = __builtin_amdgcn_mfma_f32_16x16x32_f16(av, Bw[kk][0], acc[mt][0], 0, 0, 0);
            acc[mt][1] = __builtin_amdgcn_mfma_f32_16x16x32_f16(av, Bw[kk][1], acc[mt][1], 0, 0, 0);
            acc[mt][2] = __builtin_amdgcn_mfma_f32_16x16x32_f16(av, Bw[kk][2], acc[mt][2], 0, 0, 0);
            acc[mt][3] = __builtin_amdgcn_mfma_f32_16x16x32_f16(av, Bw[kk][3], acc[mt][3], 0, 0, 0);
        }

        // ---- 8-way K-split reduction ----
#pragma unroll
        for (int mt = 0; mt < 2; ++mt)
#pragma unroll
            for (int nt = 0; nt < 4; ++nt)
                red[mt][wave][nt][lane] = acc[mt][nt];
        __syncthreads();                          // barrier A (red ready;
                                                  // also: all 32 flags seen)

        // ---- per-wave owner epilogue: sum, tanh, transpose, publish ----
        {
            float xr[4];
#pragma unroll
            for (int r = 0; r < 4; ++r) xr[r] = xs[t][mtO * 16 + quad * 4 + r];
            floatx4 s = red[mtO][0][ntO][lane];
#pragma unroll
            for (int ww = 1; ww < 8; ++ww) s += red[mtO][ww][ntO][lane];
#pragma unroll
            for (int r = 0; r < 4; ++r) {
                const float pre = s[r] + xr[r] * uvO + bvO;
                Tr[wave][quad * 4 + r][lq] = fast_tanh(pre);   // wave-private
            }
            // DS pipe is in-order within a wave: read back transposed
            const float4 fr = *(const float4*)&Tr[wave][lq][quad * 4];

            if (t < T_ - 1) {
                half4v hv;
                hv[0] = (half_t)fr.x; hv[1] = (half_t)fr.y;
                hv[2] = (half_t)fr.z; hv[3] = (half_t)fr.w;
                publish_u64(pout + pdst_o, __builtin_bit_cast(u64, hv));
                __syncthreads();      // barrier B: drains ALL waves' vmcnt
                if (tid == 0)         // single aggregated signal
                    __hip_atomic_fetch_add(
                        myflag_base + (size_t)t * (8 * 32 * 32), 1u,
                        __ATOMIC_RELAXED, __HIP_MEMORY_SCOPE_AGENT);
            } else {
                // final h_128 -> d_out fp32
                float* fd = hf32 + (size_t)(m0 + mtO * 16 + lq) * H_
                          + n0 + ntO * 16 + quad * 4;
                *(float4*)fd = make_float4(fr.x, fr.y, fr.z, fr.w);
                __syncthreads();      // all waves' Tr tiles complete
                // fused projection: partial out[32,10] = Tr-tiles @ V^T
                if (tid < 32 * C_) {
                    const int r = tid & 31, c = tid >> 5;    // c in [0,10)
                    float sacc = (C == 0) ? bp[c] : 0.0f;
                    const float* vr = V + (size_t)c * H_ + n0;
#pragma unroll 8
                    for (int n = 0; n < 64; ++n)
                        sacc += Tr[(n >> 4) * 2 + (r >> 4)][r & 15][n & 15] * vr[n];
                    atomicAdd(&outp[(size_t)(m0 + r) * C_ + c], sacc);
                }
            }
        }
    }
}

extern "C" void kernel_launch(void* const* d_in, const int* in_sizes, int n_in,
                              void* d_out, int out_size, void* d_ws, size_t ws_size,
                              hipStream_t stream) {
    const float* x  = (const float*)d_in[0];
    const float* U  = (const float*)d_in[1];
    const float* W  = (const float*)d_in[2];
    const float* V  = (const float*)d_in[3];
    const float* bh = (const float*)d_in[4];
    const float* bp = (const float*)d_in[5];

    float* out_h = (float*)d_out;                 // [B_*H_] fp32 h_last
    float* outp  = out_h + (size_t)B_ * H_;       // [B_*C_]

    unsigned* flags = (unsigned*)d_ws;                              // 4 MB
    half_t* hbase = (half_t*)((char*)d_ws + (size_t)4 * 1024 * 1024);

    // rotation needs 4 MB flags + 127 x 1 MB slots = 131 MB
    const size_t need = (size_t)(4 + NSLOT) * 1024 * 1024;
    const int rot = ws_size >= need;

    hipMemsetAsync(flags, 0, FLAG_DWORDS * sizeof(unsigned), stream);
    hipMemsetAsync(outp, 0, (size_t)B_ * C_ * sizeof(float), stream);

    if (rot)
        rnn_persist<1><<<dim3(256), dim3(512), 0, stream>>>(
            x, U, W, bh, V, bp, hbase, out_h, outp, flags);
    else
        rnn_persist<0><<<dim3(256), dim3(512), 0, stream>>>(
            x, U, W, bh, V, bp, hbase, out_h, outp, flags);
}